// Round 1
// baseline (1329.707 us; speedup 1.0000x reference)
//
#include <hip/hip_runtime.h>

#define NN 100000        // nodes
#define NE 1600000       // edges
#define NRL 3            // relations
#define NG 1024          // graphs
#define NSEG (NRL * NN)  // 300000 segments
#define SCAN_BLOCK 1024
#define SCAN_NB ((NSEG + SCAN_BLOCK - 1) / SCAN_BLOCK)  // 293

// ---------------- embed + lin0 + relu ----------------
__global__ void k_embed(const int* __restrict__ x_idx,
                        const float* __restrict__ semb, const float* __restrict__ cemb,
                        const float* __restrict__ w, const float* __restrict__ b,
                        float* __restrict__ xout) {
    __shared__ float s_w[16 * 64];
    __shared__ float s_se[64], s_ce[64], s_b[64];
    int t = threadIdx.x;
    for (int i = t; i < 16 * 64; i += 256) s_w[i] = w[i];
    if (t < 64) { s_se[t] = semb[t]; s_ce[t] = cemb[t]; s_b[t] = b[t]; }
    __syncthreads();
    int gid = blockIdx.x * 256 + t;           // grid exactly NN*64/256
    int v = gid >> 6, h = gid & 63;
    int si = x_idx[2 * v], ci = x_idx[2 * v + 1];
    float acc = s_b[h];
#pragma unroll
    for (int d = 0; d < 8; ++d) acc += s_se[si * 8 + d] * s_w[d * 64 + h];
#pragma unroll
    for (int d = 0; d < 8; ++d) acc += s_ce[ci * 8 + d] * s_w[(8 + d) * 64 + h];
    xout[gid] = fmaxf(acc, 0.f);
}

// ---------------- CSR build ----------------
__global__ void k_hist(const int* __restrict__ ei, const int* __restrict__ et,
                       int* __restrict__ cnt) {
    int e = blockIdx.x * 256 + threadIdx.x;
    if (e >= NE) return;
    int dst = ei[NE + e];
    atomicAdd(&cnt[dst * 3 + et[e]], 1);
}

__global__ void k_scan_reduce(const int* __restrict__ cnt, int* __restrict__ bsum) {
    __shared__ int lds[256];
    int blk = blockIdx.x, t = threadIdx.x;
    int base = blk * SCAN_BLOCK + t * 4;
    int s = 0;
#pragma unroll
    for (int j = 0; j < 4; ++j) { int idx = base + j; if (idx < NSEG) s += cnt[idx]; }
    lds[t] = s; __syncthreads();
    for (int ofs = 128; ofs > 0; ofs >>= 1) {
        if (t < ofs) lds[t] += lds[t + ofs];
        __syncthreads();
    }
    if (t == 0) bsum[blk] = lds[0];
}

__global__ void k_scan_top(const int* __restrict__ bsum, int* __restrict__ goff,
                           int* __restrict__ off_last) {
    __shared__ int lds[512];
    int t = threadIdx.x;
    int v = (t < SCAN_NB) ? bsum[t] : 0;
    lds[t] = v; __syncthreads();
    for (int ofs = 1; ofs < 512; ofs <<= 1) {
        int x = lds[t];
        int y = (t >= ofs) ? lds[t - ofs] : 0;
        __syncthreads();
        lds[t] = x + y;
        __syncthreads();
    }
    if (t < SCAN_NB) goff[t] = lds[t] - v;     // exclusive block offsets
    if (t == SCAN_NB - 1) *off_last = lds[t];  // total = NE
}

__global__ void k_scan_final(const int* __restrict__ cnt, const int* __restrict__ goff,
                             int* __restrict__ off, int* __restrict__ pos) {
    __shared__ int lds[256];
    int blk = blockIdx.x, t = threadIdx.x;
    int base = blk * SCAN_BLOCK + t * 4;
    int v[4]; int s = 0;
#pragma unroll
    for (int j = 0; j < 4; ++j) { int idx = base + j; v[j] = (idx < NSEG) ? cnt[idx] : 0; s += v[j]; }
    lds[t] = s; __syncthreads();
    for (int ofs = 1; ofs < 256; ofs <<= 1) {
        int x = lds[t];
        int y = (t >= ofs) ? lds[t - ofs] : 0;
        __syncthreads();
        lds[t] = x + y;
        __syncthreads();
    }
    int run = goff[blk] + (lds[t] - s);
#pragma unroll
    for (int j = 0; j < 4; ++j) {
        int idx = base + j;
        if (idx < NSEG) { off[idx] = run; pos[idx] = run; run += v[j]; }
    }
}

__global__ void k_scatter(const int* __restrict__ ei, const int* __restrict__ et,
                          int* __restrict__ pos, int* __restrict__ esrc) {
    int e = blockIdx.x * 256 + threadIdx.x;
    if (e >= NE) return;
    int src = ei[e];
    int dst = ei[NE + e];
    int p = atomicAdd(&pos[dst * 3 + et[e]], 1);
    esrc[p] = src;
}

// ---------------- per-(r,dst) mean aggregation: wave per node ----------------
// Writes K[v][0:64)=mean_r0, [64:128)=mean_r1, [128:192)=mean_r2, [192:256)=x[v]
__global__ void k_agg(const float* __restrict__ xin, const int* __restrict__ off,
                      const int* __restrict__ esrc, float* __restrict__ K) {
    int wid = (blockIdx.x * 256 + threadIdx.x) >> 6;
    int lane = threadIdx.x & 63;
    if (wid >= NN) return;
    int v = wid;
    float* Kv = K + (size_t)v * 256;
#pragma unroll
    for (int r = 0; r < 3; ++r) {
        int s0 = off[v * 3 + r], s1 = off[v * 3 + r + 1];
        float acc = 0.f;
        for (int e = s0; e < s1; ++e) {
            int s = esrc[e];                       // uniform across wave
            acc += xin[(size_t)s * 64 + lane];     // coalesced 256B gather
        }
        Kv[r * 64 + lane] = acc / fmaxf((float)(s1 - s0), 1.f);
    }
    Kv[192 + lane] = xin[(size_t)v * 64 + lane];
}

// ---------------- dense transform: xout = relu(K @ [Wr0;Wr1;Wr2;Wroot] + b) ----------------
__global__ void k_transform(const float* __restrict__ K, const float* __restrict__ wrel,
                            const float* __restrict__ wroot, const float* __restrict__ b,
                            float* __restrict__ xout) {
    int gid = blockIdx.x * 256 + threadIdx.x;   // grid exactly NN*64/256
    int v = gid >> 6, h = gid & 63;
    const float* Kv = K + (size_t)v * 256;
    float acc = b[h];
    for (int r = 0; r < 3; ++r) {
        const float* W = wrel + r * 4096;
        const float* kk = Kv + r * 64;
#pragma unroll
        for (int d4 = 0; d4 < 16; ++d4) {
            float4 k4 = *reinterpret_cast<const float4*>(kk + d4 * 4);
            acc += k4.x * W[(d4 * 4 + 0) * 64 + h];
            acc += k4.y * W[(d4 * 4 + 1) * 64 + h];
            acc += k4.z * W[(d4 * 4 + 2) * 64 + h];
            acc += k4.w * W[(d4 * 4 + 3) * 64 + h];
        }
    }
    {
        const float* kk = Kv + 192;
#pragma unroll
        for (int d4 = 0; d4 < 16; ++d4) {
            float4 k4 = *reinterpret_cast<const float4*>(kk + d4 * 4);
            acc += k4.x * wroot[(d4 * 4 + 0) * 64 + h];
            acc += k4.y * wroot[(d4 * 4 + 1) * 64 + h];
            acc += k4.z * wroot[(d4 * 4 + 2) * 64 + h];
            acc += k4.w * wroot[(d4 * 4 + 3) * 64 + h];
        }
    }
    xout[gid] = fmaxf(acc, 0.f);
}

// ---------------- global mean pool (atomics) + classifier ----------------
__global__ void k_pool(const float* __restrict__ x, const int* __restrict__ batch,
                       float* __restrict__ psum, int* __restrict__ pcnt) {
    int gid = blockIdx.x * 256 + threadIdx.x;
    int v = gid >> 6, h = gid & 63;
    atomicAdd(&psum[batch[v] * 64 + h], x[gid]);
    if (h == 0) atomicAdd(&pcnt[batch[v]], 1);
}

__global__ void k_cls(const float* __restrict__ psum, const int* __restrict__ pcnt,
                      const float* __restrict__ w, const float* __restrict__ b,
                      float* __restrict__ out) {
    int gid = blockIdx.x * 256 + threadIdx.x;
    if (gid >= NG * 10) return;
    int g = gid / 10, c = gid % 10;
    float inv = 1.f / fmaxf((float)pcnt[g], 1.f);
    float acc = 0.f;
#pragma unroll
    for (int d = 0; d < 64; ++d) acc += psum[g * 64 + d] * w[d * 10 + c];
    out[gid] = acc * inv + b[c];
}

extern "C" void kernel_launch(void* const* d_in, const int* in_sizes, int n_in,
                              void* d_out, int out_size, void* d_ws, size_t ws_size,
                              hipStream_t stream) {
    const int*   x_idx  = (const int*)d_in[0];
    const int*   ei     = (const int*)d_in[1];
    const int*   et     = (const int*)d_in[2];
    const int*   batch  = (const int*)d_in[3];
    const float* semb   = (const float*)d_in[4];
    const float* cemb   = (const float*)d_in[5];
    const float* lin0w  = (const float*)d_in[6];
    const float* lin0b  = (const float*)d_in[7];
    const float* r1wrel = (const float*)d_in[8];
    const float* r1wroot= (const float*)d_in[9];
    const float* r1b    = (const float*)d_in[10];
    const float* r2wrel = (const float*)d_in[11];
    const float* r2wroot= (const float*)d_in[12];
    const float* r2b    = (const float*)d_in[13];
    const float* clsw   = (const float*)d_in[14];
    const float* clsb   = (const float*)d_in[15];
    float* out = (float*)d_out;

    char* ws = (char*)d_ws;
    size_t o = 0;
    auto alloc = [&](size_t bytes) -> void* {
        void* p = ws + o;
        o += (bytes + 255) & ~(size_t)255;
        return p;
    };
    int*   off  = (int*)  alloc((size_t)(NSEG + 1) * 4);
    int*   pos  = (int*)  alloc((size_t)NSEG * 4);
    int*   cnt  = (int*)  alloc((size_t)NSEG * 4);
    int*   bsum = (int*)  alloc((size_t)SCAN_NB * 4);
    int*   goff = (int*)  alloc((size_t)SCAN_NB * 4);
    int*   esrc = (int*)  alloc((size_t)NE * 4);
    float* xA   = (float*)alloc((size_t)NN * 64 * 4);
    float* xB   = (float*)alloc((size_t)NN * 64 * 4);
    float* Kbuf = (float*)alloc((size_t)NN * 256 * 4);
    float* psum = (float*)alloc((size_t)NG * 64 * 4);
    int*   pcnt = (int*)  alloc((size_t)NG * 4);

    hipMemsetAsync(cnt, 0, (size_t)NSEG * 4, stream);
    hipMemsetAsync(psum, 0, (size_t)NG * 64 * 4, stream);
    hipMemsetAsync(pcnt, 0, (size_t)NG * 4, stream);

    // node features
    k_embed<<<NN * 64 / 256, 256, 0, stream>>>(x_idx, semb, cemb, lin0w, lin0b, xA);

    // CSR (built once, reused for both layers)
    k_hist<<<NE / 256, 256, 0, stream>>>(ei, et, cnt);
    k_scan_reduce<<<SCAN_NB, 256, 0, stream>>>(cnt, bsum);
    k_scan_top<<<1, 512, 0, stream>>>(bsum, goff, off + NSEG);
    k_scan_final<<<SCAN_NB, 256, 0, stream>>>(cnt, goff, off, pos);
    k_scatter<<<NE / 256, 256, 0, stream>>>(ei, et, pos, esrc);

    // layer 1
    k_agg<<<NN / 4, 256, 0, stream>>>(xA, off, esrc, Kbuf);
    k_transform<<<NN * 64 / 256, 256, 0, stream>>>(Kbuf, r1wrel, r1wroot, r1b, xB);
    // layer 2
    k_agg<<<NN / 4, 256, 0, stream>>>(xB, off, esrc, Kbuf);
    k_transform<<<NN * 64 / 256, 256, 0, stream>>>(Kbuf, r2wrel, r2wroot, r2b, xA);

    // pool + classify
    k_pool<<<NN * 64 / 256, 256, 0, stream>>>(xA, batch, psum, pcnt);
    k_cls<<<(NG * 10 + 255) / 256, 256, 0, stream>>>(psum, pcnt, clsw, clsb, out);
}

// Round 2
// 935.520 us; speedup vs baseline: 1.4214x; 1.4214x over previous
//
#include <hip/hip_runtime.h>

#define NN 100000        // nodes
#define NE 1600000       // edges
#define NRL 3            // relations
#define NG 1024          // graphs
#define NSEG (NRL * NN)  // 300000 segments
#define SCAN_BLOCK 1024
#define SCAN_NB ((NSEG + SCAN_BLOCK - 1) / SCAN_BLOCK)  // 293

// ---------------- embed + lin0 + relu ----------------
__global__ void k_embed(const int* __restrict__ x_idx,
                        const float* __restrict__ semb, const float* __restrict__ cemb,
                        const float* __restrict__ w, const float* __restrict__ b,
                        float* __restrict__ xout) {
    __shared__ float s_w[16 * 64];
    __shared__ float s_se[64], s_ce[64], s_b[64];
    int t = threadIdx.x;
    for (int i = t; i < 16 * 64; i += 256) s_w[i] = w[i];
    if (t < 64) { s_se[t] = semb[t]; s_ce[t] = cemb[t]; s_b[t] = b[t]; }
    __syncthreads();
    int gid = blockIdx.x * 256 + t;           // grid exactly NN*64/256
    int v = gid >> 6, h = gid & 63;
    int si = x_idx[2 * v], ci = x_idx[2 * v + 1];
    float acc = s_b[h];
#pragma unroll
    for (int d = 0; d < 8; ++d) acc += s_se[si * 8 + d] * s_w[d * 64 + h];
#pragma unroll
    for (int d = 0; d < 8; ++d) acc += s_ce[ci * 8 + d] * s_w[(8 + d) * 64 + h];
    xout[gid] = fmaxf(acc, 0.f);
}

// ---------------- CSR build ----------------
__global__ void k_hist(const int* __restrict__ ei, const int* __restrict__ et,
                       int* __restrict__ cnt) {
    int e = blockIdx.x * 256 + threadIdx.x;
    if (e >= NE) return;
    int dst = ei[NE + e];
    atomicAdd(&cnt[dst * 3 + et[e]], 1);
}

__global__ void k_scan_reduce(const int* __restrict__ cnt, int* __restrict__ bsum) {
    __shared__ int lds[256];
    int blk = blockIdx.x, t = threadIdx.x;
    int base = blk * SCAN_BLOCK + t * 4;
    int s = 0;
#pragma unroll
    for (int j = 0; j < 4; ++j) { int idx = base + j; if (idx < NSEG) s += cnt[idx]; }
    lds[t] = s; __syncthreads();
    for (int ofs = 128; ofs > 0; ofs >>= 1) {
        if (t < ofs) lds[t] += lds[t + ofs];
        __syncthreads();
    }
    if (t == 0) bsum[blk] = lds[0];
}

__global__ void k_scan_top(const int* __restrict__ bsum, int* __restrict__ goff,
                           int* __restrict__ off_last) {
    __shared__ int lds[512];
    int t = threadIdx.x;
    int v = (t < SCAN_NB) ? bsum[t] : 0;
    lds[t] = v; __syncthreads();
    for (int ofs = 1; ofs < 512; ofs <<= 1) {
        int x = lds[t];
        int y = (t >= ofs) ? lds[t - ofs] : 0;
        __syncthreads();
        lds[t] = x + y;
        __syncthreads();
    }
    if (t < SCAN_NB) goff[t] = lds[t] - v;     // exclusive block offsets
    if (t == SCAN_NB - 1) *off_last = lds[t];  // total = NE
}

__global__ void k_scan_final(const int* __restrict__ cnt, const int* __restrict__ goff,
                             int* __restrict__ off, int* __restrict__ pos) {
    __shared__ int lds[256];
    int blk = blockIdx.x, t = threadIdx.x;
    int base = blk * SCAN_BLOCK + t * 4;
    int v[4]; int s = 0;
#pragma unroll
    for (int j = 0; j < 4; ++j) { int idx = base + j; v[j] = (idx < NSEG) ? cnt[idx] : 0; s += v[j]; }
    lds[t] = s; __syncthreads();
    for (int ofs = 1; ofs < 256; ofs <<= 1) {
        int x = lds[t];
        int y = (t >= ofs) ? lds[t - ofs] : 0;
        __syncthreads();
        lds[t] = x + y;
        __syncthreads();
    }
    int run = goff[blk] + (lds[t] - s);
#pragma unroll
    for (int j = 0; j < 4; ++j) {
        int idx = base + j;
        if (idx < NSEG) { off[idx] = run; pos[idx] = run; run += v[j]; }
    }
}

__global__ void k_scatter(const int* __restrict__ ei, const int* __restrict__ et,
                          int* __restrict__ pos, int* __restrict__ esrc) {
    int e = blockIdx.x * 256 + threadIdx.x;
    if (e >= NE) return;
    int src = ei[e];
    int dst = ei[NE + e];
    int p = atomicAdd(&pos[dst * 3 + et[e]], 1);
    esrc[p] = src;
}

// ---------------- per-(r,dst) mean aggregation: wave per node ----------------
// Writes K[v][0:64)=mean_r0, [64:128)=mean_r1, [128:192)=mean_r2, [192:256)=x[v]
__global__ void k_agg(const float* __restrict__ xin, const int* __restrict__ off,
                      const int* __restrict__ esrc, float* __restrict__ K) {
    int wid = (blockIdx.x * 256 + threadIdx.x) >> 6;
    int lane = threadIdx.x & 63;
    if (wid >= NN) return;
    int v = wid;
    float* Kv = K + (size_t)v * 256;
#pragma unroll
    for (int r = 0; r < 3; ++r) {
        int s0 = off[v * 3 + r], s1 = off[v * 3 + r + 1];
        float acc = 0.f;
        int e = s0;
        for (; e + 4 <= s1; e += 4) {
            int i0 = esrc[e], i1 = esrc[e + 1], i2 = esrc[e + 2], i3 = esrc[e + 3];
            float x0 = xin[(size_t)i0 * 64 + lane];
            float x1 = xin[(size_t)i1 * 64 + lane];
            float x2 = xin[(size_t)i2 * 64 + lane];
            float x3 = xin[(size_t)i3 * 64 + lane];
            acc += (x0 + x1) + (x2 + x3);
        }
        for (; e < s1; ++e) acc += xin[(size_t)esrc[e] * 64 + lane];
        Kv[r * 64 + lane] = acc / fmaxf((float)(s1 - s0), 1.f);
    }
    Kv[192 + lane] = xin[(size_t)v * 64 + lane];
}

// ---------------- dense transform: xout = relu(K @ [Wr0;Wr1;Wr2;Wroot] + b) ----------------
// Block = 512 threads (8 waves). Wave handles 8 nodes, lane = h.
// Wcat (256x64 = 64KB) staged in LDS; each LDS W read feeds 8 FMAs.
__global__ __launch_bounds__(512, 4) void k_transform(
        const float* __restrict__ K, const float* __restrict__ wrel,
        const float* __restrict__ wroot, const float* __restrict__ b,
        float* __restrict__ xout) {
    __shared__ float s_w[256 * 64];   // rows 0..191 = wrel (r,din), rows 192..255 = wroot
    __shared__ float s_b[64];
    int t = threadIdx.x;
    for (int i = t; i < 192 * 64; i += 512) s_w[i] = wrel[i];
    for (int i = t; i < 64 * 64; i += 512) s_w[192 * 64 + i] = wroot[i];
    if (t < 64) s_b[t] = b[t];
    __syncthreads();

    int wave = t >> 6, lane = t & 63;
    int v0 = blockIdx.x * 64 + wave * 8;   // 8 waves * 8 nodes = 64 nodes/block

    const float* Kp[8];
    float acc[8];
    float bb = s_b[lane];
#pragma unroll
    for (int n = 0; n < 8; ++n) {
        int v = v0 + n;
        if (v >= NN) v = NN - 1;           // clamp tail (store is guarded below)
        Kp[n] = K + (size_t)v * 256;
        acc[n] = bb;
    }

    for (int d4 = 0; d4 < 64; ++d4) {
        float w0 = s_w[(d4 * 4 + 0) * 64 + lane];
        float w1 = s_w[(d4 * 4 + 1) * 64 + lane];
        float w2 = s_w[(d4 * 4 + 2) * 64 + lane];
        float w3 = s_w[(d4 * 4 + 3) * 64 + lane];
#pragma unroll
        for (int n = 0; n < 8; ++n) {
            float4 p = *reinterpret_cast<const float4*>(Kp[n] + d4 * 4);
            acc[n] += p.x * w0 + p.y * w1 + p.z * w2 + p.w * w3;
        }
    }

#pragma unroll
    for (int n = 0; n < 8; ++n) {
        int v = v0 + n;
        if (v < NN) xout[(size_t)v * 64 + lane] = fmaxf(acc[n], 0.f);
    }
}

// ---------------- global mean pool (atomics) + classifier ----------------
__global__ void k_pool(const float* __restrict__ x, const int* __restrict__ batch,
                       float* __restrict__ psum, int* __restrict__ pcnt) {
    int gid = blockIdx.x * 256 + threadIdx.x;
    int v = gid >> 6, h = gid & 63;
    atomicAdd(&psum[batch[v] * 64 + h], x[gid]);
    if (h == 0) atomicAdd(&pcnt[batch[v]], 1);
}

__global__ void k_cls(const float* __restrict__ psum, const int* __restrict__ pcnt,
                      const float* __restrict__ w, const float* __restrict__ b,
                      float* __restrict__ out) {
    int gid = blockIdx.x * 256 + threadIdx.x;
    if (gid >= NG * 10) return;
    int g = gid / 10, c = gid % 10;
    float inv = 1.f / fmaxf((float)pcnt[g], 1.f);
    float acc = 0.f;
#pragma unroll
    for (int d = 0; d < 64; ++d) acc += psum[g * 64 + d] * w[d * 10 + c];
    out[gid] = acc * inv + b[c];
}

extern "C" void kernel_launch(void* const* d_in, const int* in_sizes, int n_in,
                              void* d_out, int out_size, void* d_ws, size_t ws_size,
                              hipStream_t stream) {
    const int*   x_idx  = (const int*)d_in[0];
    const int*   ei     = (const int*)d_in[1];
    const int*   et     = (const int*)d_in[2];
    const int*   batch  = (const int*)d_in[3];
    const float* semb   = (const float*)d_in[4];
    const float* cemb   = (const float*)d_in[5];
    const float* lin0w  = (const float*)d_in[6];
    const float* lin0b  = (const float*)d_in[7];
    const float* r1wrel = (const float*)d_in[8];
    const float* r1wroot= (const float*)d_in[9];
    const float* r1b    = (const float*)d_in[10];
    const float* r2wrel = (const float*)d_in[11];
    const float* r2wroot= (const float*)d_in[12];
    const float* r2b    = (const float*)d_in[13];
    const float* clsw   = (const float*)d_in[14];
    const float* clsb   = (const float*)d_in[15];
    float* out = (float*)d_out;

    char* ws = (char*)d_ws;
    size_t o = 0;
    auto alloc = [&](size_t bytes) -> void* {
        void* p = ws + o;
        o += (bytes + 255) & ~(size_t)255;
        return p;
    };
    int*   off  = (int*)  alloc((size_t)(NSEG + 1) * 4);
    int*   pos  = (int*)  alloc((size_t)NSEG * 4);
    int*   cnt  = (int*)  alloc((size_t)NSEG * 4);
    int*   bsum = (int*)  alloc((size_t)SCAN_NB * 4);
    int*   goff = (int*)  alloc((size_t)SCAN_NB * 4);
    int*   esrc = (int*)  alloc((size_t)NE * 4);
    float* xA   = (float*)alloc((size_t)NN * 64 * 4);
    float* xB   = (float*)alloc((size_t)NN * 64 * 4);
    float* Kbuf = (float*)alloc((size_t)NN * 256 * 4);
    float* psum = (float*)alloc((size_t)NG * 64 * 4);
    int*   pcnt = (int*)  alloc((size_t)NG * 4);

    hipMemsetAsync(cnt, 0, (size_t)NSEG * 4, stream);
    hipMemsetAsync(psum, 0, (size_t)NG * 64 * 4, stream);
    hipMemsetAsync(pcnt, 0, (size_t)NG * 4, stream);

    // node features
    k_embed<<<NN * 64 / 256, 256, 0, stream>>>(x_idx, semb, cemb, lin0w, lin0b, xA);

    // CSR (built once, reused for both layers)
    k_hist<<<NE / 256, 256, 0, stream>>>(ei, et, cnt);
    k_scan_reduce<<<SCAN_NB, 256, 0, stream>>>(cnt, bsum);
    k_scan_top<<<1, 512, 0, stream>>>(bsum, goff, off + NSEG);
    k_scan_final<<<SCAN_NB, 256, 0, stream>>>(cnt, goff, off, pos);
    k_scatter<<<NE / 256, 256, 0, stream>>>(ei, et, pos, esrc);

    // layer 1
    k_agg<<<NN / 4, 256, 0, stream>>>(xA, off, esrc, Kbuf);
    k_transform<<<(NN + 63) / 64, 512, 0, stream>>>(Kbuf, r1wrel, r1wroot, r1b, xB);
    // layer 2
    k_agg<<<NN / 4, 256, 0, stream>>>(xB, off, esrc, Kbuf);
    k_transform<<<(NN + 63) / 64, 512, 0, stream>>>(Kbuf, r2wrel, r2wroot, r2b, xA);

    // pool + classify
    k_pool<<<NN * 64 / 256, 256, 0, stream>>>(xA, batch, psum, pcnt);
    k_cls<<<(NG * 10 + 255) / 256, 256, 0, stream>>>(psum, pcnt, clsw, clsb, out);
}